// Round 5
// baseline (40223.779 us; speedup 1.0000x reference)
//
#include <hip/hip_runtime.h>

typedef unsigned short ushort_t;
typedef __attribute__((ext_vector_type(8))) short short8;
typedef __attribute__((ext_vector_type(4))) float f32x4;
typedef __attribute__((ext_vector_type(4))) int i32x4;

#define NB   256     // batch
#define NT   512     // timesteps
#define ND   512     // input dim
#define NH   1024    // hidden dim
#define KK   1536    // NH + ND (concatenated K)

#define GROUPS      8    // independent batch groups
#define ROWS_PER_G  32   // batch rows per group
#define BLKS_PER_G  64   // blocks per group (n-partitions)
#define NBLK        512  // total blocks (2 per CU)
#define KW          384  // K-range per wave (4-way K-split)
#define KS          12   // K-steps of 32 per wave

__device__ __forceinline__ ushort_t f2bf(float f) {
  union { float f; unsigned u; } v; v.f = f;
  unsigned u = v.u;
  return (ushort_t)((u + 0x7FFFu + ((u >> 16) & 1u)) >> 16);
}
__device__ __forceinline__ int pack2(float a, float b) {
  return (int)(((unsigned)f2bf(b) << 16) | (unsigned)f2bf(a));
}
__device__ __forceinline__ float sigmoidf_(float x) {
  return 1.f / (1.f + __expf(-x));
}
__device__ __forceinline__ float tanhf_(float x) {
  return 1.f - 2.f / (__expf(2.f * x) + 1.f);
}

// ---------------------------------------------------------------------------
// Repack weights to bf16, N-major (k-contiguous). Verified in rounds 2/4.
//   B1t [2048][1536]: cols 0..1023 = z ([U_z;W_z]), 1024..2047 = r ([U_r;W_r])
//   B2t [1024][1536]: candidate ([U;W])
// ---------------------------------------------------------------------------
__global__ void repack_weights(const float* __restrict__ U,  const float* __restrict__ W,
                               const float* __restrict__ Uz, const float* __restrict__ Wz,
                               const float* __restrict__ Ur, const float* __restrict__ Wr,
                               ushort_t* __restrict__ B1t, ushort_t* __restrict__ B2t) {
  const int kt = blockIdx.x, nt = blockIdx.y, which = blockIdx.z;
  if (which == 1 && nt >= 16) return;
  __shared__ float tile[64][65];
  const int k0 = kt * 64, n0 = nt * 64;
  const int tid = threadIdx.x;
  for (int i = 0; i < 16; ++i) {
    int e = tid + i * 256;
    int r = e >> 6, c = e & 63;
    int k = k0 + r, n = n0 + c;
    int nn = n & 1023;
    const float* src;
    if (which == 0) {
      if (k < NH) src = (n < NH ? Uz : Ur) + (size_t)k * NH + nn;
      else        src = (n < NH ? Wz : Wr) + (size_t)(k - NH) * NH + nn;
    } else {
      if (k < NH) src = U + (size_t)k * NH + nn;
      else        src = W + (size_t)(k - NH) * NH + nn;
    }
    tile[r][c] = *src;
  }
  __syncthreads();
  ushort_t* dst = (which == 0) ? B1t : B2t;
  for (int i = 0; i < 2; ++i) {
    int cch = tid + i * 256;
    int nl = cch >> 3, kc = (cch & 7) * 8;
    ushort_t tmp[8];
#pragma unroll
    for (int j = 0; j < 8; ++j) tmp[j] = f2bf(tile[kc + j][nl]);
    *reinterpret_cast<i32x4*>(dst + (size_t)(n0 + nl) * KK + k0 + kc) =
        *reinterpret_cast<i32x4*>(tmp);
  }
}

__global__ void init_state(ushort_t* __restrict__ hb, float* __restrict__ hf,
                           unsigned* __restrict__ flags) {
  int i = blockIdx.x * 256 + threadIdx.x;
  if (i < NB * NH) { hb[i] = 0; hf[i] = 0.f; }
  if (i < GROUPS * BLKS_PER_G) flags[i] = 0u;
}

// x f32 -> bf16, [B][T][D] layout preserved.
__global__ void xconvert(const float* __restrict__ x, ushort_t* __restrict__ xb) {
  size_t i = ((size_t)blockIdx.x * 256 + threadIdx.x) * 8;
  f32x4 a = *reinterpret_cast<const f32x4*>(x + i);
  f32x4 b = *reinterpret_cast<const f32x4*>(x + i + 4);
  i32x4 o;
  o[0] = pack2(a[0], a[1]); o[1] = pack2(a[2], a[3]);
  o[2] = pack2(b[0], b[1]); o[3] = pack2(b[2], b[3]);
  *reinterpret_cast<i32x4*>(xb + i) = o;
}

// ---------------------------------------------------------------------------
// Group barrier: flag-array, agent scope. Same structure as round 4 (worked).
// ---------------------------------------------------------------------------
__device__ __forceinline__ void group_barrier(unsigned* flags, int g, int slot,
                                              unsigned target, int tid) {
  __syncthreads();
  if (tid == 0) {
    __hip_atomic_store(flags + g * BLKS_PER_G + slot, target,
                       __ATOMIC_RELEASE, __HIP_MEMORY_SCOPE_AGENT);
  }
  if (tid < BLKS_PER_G) {
    while (__hip_atomic_load(flags + g * BLKS_PER_G + tid,
                             __ATOMIC_RELAXED, __HIP_MEMORY_SCOPE_AGENT) < target) {
      __builtin_amdgcn_s_sleep(4);
    }
  }
  __syncthreads();
  __builtin_amdgcn_fence(__ATOMIC_ACQUIRE, "agent");
}

// ---------------------------------------------------------------------------
// Persistent GRU v2. 512 blocks x 256 threads (2 blocks/CU, 8 waves/CU).
// Block: group g = bid>>6 (32 batch rows), slot = bid&63.
// Phase1 cols: slot*32 (of 2048); phase2 cols: slot*16 (of 1024).
// 4 waves K-split K=1536 into 384 each; weights in VGPRs (36 short8 = 144 reg).
// K-loop: branchless pointer-select loads + MFMA; epilogue operands prefetched
// before the K-loop to overlap their latency with the GEMM.
// ---------------------------------------------------------------------------
__global__ void __launch_bounds__(256, 2)
gru_persistent2(const float* __restrict__ x, const ushort_t* __restrict__ xb,
                const int useXbf,
                const ushort_t* __restrict__ B1t, const ushort_t* __restrict__ B2t,
                ushort_t* __restrict__ hb, ushort_t* __restrict__ rhb,
                float* __restrict__ hf, float* __restrict__ zfb,
                const float* __restrict__ bb, const float* __restrict__ bz,
                const float* __restrict__ br, unsigned* __restrict__ flags,
                float* __restrict__ out) {
  __shared__ __align__(16) f32x4 redbuf[1024];   // 16KB -> 2 blocks/CU fits

  const int tid  = threadIdx.x;
  const int bid  = blockIdx.x;
  const int w    = tid >> 6;
  const int lane = tid & 63;
  const int l15  = lane & 15;
  const int l4   = lane >> 4;
  const int g    = bid >> 6;
  const int slot = bid & 63;
  const int n1g  = slot * 32;       // phase1 col base (0..2047)
  const int n2g  = slot * 16;       // phase2 col base (0..1023)
  const int rowbase = g * ROWS_PER_G;
  const int kfl  = w * KW + 8 * l4; // per-lane k base

  // ---- stationary weights in registers ----
  short8 B1R[2][KS];
  short8 B2R[KS];
#pragma unroll
  for (int s = 0; s < KS; ++s) {
    int k = kfl + 32 * s;
#pragma unroll
    for (int j = 0; j < 2; ++j)
      B1R[j][s] = *reinterpret_cast<const short8*>(B1t + (size_t)(n1g + 16 * j + l15) * KK + k);
    B2R[s] = *reinterpret_cast<const short8*>(B2t + (size_t)(n2g + l15) * KK + k);
  }

  // ---- per-thread epilogue constants (fixed across t) ----
  const int col1 = n1g + (w & 1) * 16 + l15;   // phase1 tile: i=w>>1, j=w&1
  const int r0_1 = rowbase + 16 * (w >> 1) + 4 * l4;
  const float bias1 = (col1 < NH) ? bz[col1] : br[col1 - NH];
  const int col2 = n2g + l15;                  // phase2 (waves 0,1 only)
  const int r0_2 = rowbase + 16 * (w & 1) + 4 * l4;
  const float bb_r = bb[col2];

  // ---- A-row base pointers ----
  const int row0 = rowbase + l15, row1 = rowbase + 16 + l15;
  const ushort_t* hbrow0 = hb + (size_t)row0 * NH;
  const ushort_t* hbrow1 = hb + (size_t)row1 * NH;
  const ushort_t* rhrow0 = rhb + (size_t)row0 * NH;
  const ushort_t* rhrow1 = rhb + (size_t)row1 * NH;
  const ushort_t* xbr0 = xb + (size_t)row0 * NT * ND;
  const ushort_t* xbr1 = xb + (size_t)row1 * NT * ND;
  const float*    xfr0 = x + (size_t)row0 * NT * ND;
  const float*    xfr1 = x + (size_t)row1 * NT * ND;

  unsigned epoch = 0;

  for (int t = 0; t < NT; ++t) {
    const ushort_t* xr0 = xbr0 + (size_t)t * ND - NH;  // +k (k>=NH) indexes x
    const ushort_t* xr1 = xbr1 + (size_t)t * ND - NH;

    // ================= phase 1: z | r =================
    // prefetch hf for the rh epilogue (stable during phase1)
    float hfpre[4];
    if (col1 >= NH) {
      int cc = col1 - NH;
#pragma unroll
      for (int jj = 0; jj < 4; ++jj)
        hfpre[jj] = hf[(size_t)(r0_1 + jj) * NH + cc];
    }

    f32x4 acc[2][2];
#pragma unroll
    for (int i = 0; i < 2; ++i)
#pragma unroll
      for (int j = 0; j < 2; ++j) acc[i][j] = (f32x4){0.f, 0.f, 0.f, 0.f};

    if (useXbf) {
#pragma unroll
      for (int s = 0; s < KS; ++s) {
        int k = kfl + 32 * s;
        const ushort_t* p0 = (k < NH) ? (hbrow0 + k) : (xr0 + k);
        const ushort_t* p1 = (k < NH) ? (hbrow1 + k) : (xr1 + k);
        short8 a0 = *reinterpret_cast<const short8*>(p0);
        short8 a1 = *reinterpret_cast<const short8*>(p1);
        acc[0][0] = __builtin_amdgcn_mfma_f32_16x16x32_bf16(a0, B1R[0][s], acc[0][0], 0, 0, 0);
        acc[0][1] = __builtin_amdgcn_mfma_f32_16x16x32_bf16(a0, B1R[1][s], acc[0][1], 0, 0, 0);
        acc[1][0] = __builtin_amdgcn_mfma_f32_16x16x32_bf16(a1, B1R[0][s], acc[1][0], 0, 0, 0);
        acc[1][1] = __builtin_amdgcn_mfma_f32_16x16x32_bf16(a1, B1R[1][s], acc[1][1], 0, 0, 0);
      }
    } else {
#pragma unroll
      for (int s = 0; s < KS; ++s) {
        int k = kfl + 32 * s;
        short8 a0, a1;
        if (k < NH) {
          a0 = *reinterpret_cast<const short8*>(hbrow0 + k);
          a1 = *reinterpret_cast<const short8*>(hbrow1 + k);
        } else {
          int kx = k - NH;
          const float* xp0 = xfr0 + (size_t)t * ND + kx;
          const float* xp1 = xfr1 + (size_t)t * ND + kx;
          f32x4 f0 = *reinterpret_cast<const f32x4*>(xp0);
          f32x4 f1 = *reinterpret_cast<const f32x4*>(xp0 + 4);
          i32x4 v; v[0] = pack2(f0[0], f0[1]); v[1] = pack2(f0[2], f0[3]);
          v[2] = pack2(f1[0], f1[1]); v[3] = pack2(f1[2], f1[3]);
          union { i32x4 iv; short8 sv; } u0; u0.iv = v; a0 = u0.sv;
          f0 = *reinterpret_cast<const f32x4*>(xp1);
          f1 = *reinterpret_cast<const f32x4*>(xp1 + 4);
          v[0] = pack2(f0[0], f0[1]); v[1] = pack2(f0[2], f0[3]);
          v[2] = pack2(f1[0], f1[1]); v[3] = pack2(f1[2], f1[3]);
          union { i32x4 iv; short8 sv; } u1; u1.iv = v; a1 = u1.sv;
        }
        acc[0][0] = __builtin_amdgcn_mfma_f32_16x16x32_bf16(a0, B1R[0][s], acc[0][0], 0, 0, 0);
        acc[0][1] = __builtin_amdgcn_mfma_f32_16x16x32_bf16(a0, B1R[1][s], acc[0][1], 0, 0, 0);
        acc[1][0] = __builtin_amdgcn_mfma_f32_16x16x32_bf16(a1, B1R[0][s], acc[1][0], 0, 0, 0);
        acc[1][1] = __builtin_amdgcn_mfma_f32_16x16x32_bf16(a1, B1R[1][s], acc[1][1], 0, 0, 0);
      }
    }

    // ---- cross-wave K-reduction + epilogue (wave w owns tile tau=w) ----
#pragma unroll
    for (int i = 0; i < 2; ++i)
#pragma unroll
      for (int j = 0; j < 2; ++j)
        redbuf[(w * 4 + i * 2 + j) * 64 + lane] = acc[i][j];
    __syncthreads();
    {
      f32x4 v = redbuf[(0 * 4 + w) * 64 + lane];
      v += redbuf[(1 * 4 + w) * 64 + lane];
      v += redbuf[(2 * 4 + w) * 64 + lane];
      v += redbuf[(3 * 4 + w) * 64 + lane];
      if (col1 < NH) {
#pragma unroll
        for (int jj = 0; jj < 4; ++jj)
          zfb[(size_t)(r0_1 + jj) * NH + col1] = sigmoidf_(v[jj] + bias1);
      } else {
        int cc = col1 - NH;
#pragma unroll
        for (int jj = 0; jj < 4; ++jj) {
          float rv = sigmoidf_(v[jj] + bias1);
          rhb[(size_t)(r0_1 + jj) * NH + cc] = f2bf(rv * hfpre[jj]);
        }
      }
    }
    group_barrier(flags, g, slot, ++epoch, tid);

    // ================= phase 2: h_cand + update =================
    // prefetch z and old h for the update (stable during phase2)
    float zpre[4], hfpre2[4];
    if (w < 2) {
#pragma unroll
      for (int jj = 0; jj < 4; ++jj) {
        size_t idx = (size_t)(r0_2 + jj) * NH + col2;
        zpre[jj]   = zfb[idx];
        hfpre2[jj] = hf[idx];
      }
    }

    f32x4 acc2[2];
#pragma unroll
    for (int i = 0; i < 2; ++i) acc2[i] = (f32x4){0.f, 0.f, 0.f, 0.f};

    if (useXbf) {
#pragma unroll
      for (int s = 0; s < KS; ++s) {
        int k = kfl + 32 * s;
        const ushort_t* p0 = (k < NH) ? (rhrow0 + k) : (xr0 + k);
        const ushort_t* p1 = (k < NH) ? (rhrow1 + k) : (xr1 + k);
        short8 a0 = *reinterpret_cast<const short8*>(p0);
        short8 a1 = *reinterpret_cast<const short8*>(p1);
        acc2[0] = __builtin_amdgcn_mfma_f32_16x16x32_bf16(a0, B2R[s], acc2[0], 0, 0, 0);
        acc2[1] = __builtin_amdgcn_mfma_f32_16x16x32_bf16(a1, B2R[s], acc2[1], 0, 0, 0);
      }
    } else {
#pragma unroll
      for (int s = 0; s < KS; ++s) {
        int k = kfl + 32 * s;
        short8 a0, a1;
        if (k < NH) {
          a0 = *reinterpret_cast<const short8*>(rhrow0 + k);
          a1 = *reinterpret_cast<const short8*>(rhrow1 + k);
        } else {
          int kx = k - NH;
          const float* xp0 = xfr0 + (size_t)t * ND + kx;
          const float* xp1 = xfr1 + (size_t)t * ND + kx;
          f32x4 f0 = *reinterpret_cast<const f32x4*>(xp0);
          f32x4 f1 = *reinterpret_cast<const f32x4*>(xp0 + 4);
          i32x4 v; v[0] = pack2(f0[0], f0[1]); v[1] = pack2(f0[2], f0[3]);
          v[2] = pack2(f1[0], f1[1]); v[3] = pack2(f1[2], f1[3]);
          union { i32x4 iv; short8 sv; } u0; u0.iv = v; a0 = u0.sv;
          f0 = *reinterpret_cast<const f32x4*>(xp1);
          f1 = *reinterpret_cast<const f32x4*>(xp1 + 4);
          v[0] = pack2(f0[0], f0[1]); v[1] = pack2(f0[2], f0[3]);
          v[2] = pack2(f1[0], f1[1]); v[3] = pack2(f1[2], f1[3]);
          union { i32x4 iv; short8 sv; } u1; u1.iv = v; a1 = u1.sv;
        }
        acc2[0] = __builtin_amdgcn_mfma_f32_16x16x32_bf16(a0, B2R[s], acc2[0], 0, 0, 0);
        acc2[1] = __builtin_amdgcn_mfma_f32_16x16x32_bf16(a1, B2R[s], acc2[1], 0, 0, 0);
      }
    }

    // ---- reduction + epilogue (waves 0,1 own tiles i=0,1) ----
#pragma unroll
    for (int i = 0; i < 2; ++i)
      redbuf[(w * 2 + i) * 64 + lane] = acc2[i];
    __syncthreads();
    if (w < 2) {
      f32x4 v = redbuf[(0 * 2 + w) * 64 + lane];
      v += redbuf[(1 * 2 + w) * 64 + lane];
      v += redbuf[(2 * 2 + w) * 64 + lane];
      v += redbuf[(3 * 2 + w) * 64 + lane];
#pragma unroll
      for (int jj = 0; jj < 4; ++jj) {
        size_t idx = (size_t)(r0_2 + jj) * NH + col2;
        float hc = tanhf_(v[jj] + bb_r);
        float zv = zpre[jj];
        float hn = (1.f - zv) * hfpre2[jj] + zv * hc;
        hf[idx] = hn;
        hb[idx] = f2bf(hn);
        if (t == NT - 1) out[idx] = hn;
      }
    }
    group_barrier(flags, g, slot, ++epoch, tid);
  }
}

extern "C" void kernel_launch(void* const* d_in, const int* in_sizes, int n_in,
                              void* d_out, int out_size, void* d_ws, size_t ws_size,
                              hipStream_t stream) {
  const float* x  = (const float*)d_in[0];
  const float* W  = (const float*)d_in[1];
  const float* U  = (const float*)d_in[2];
  const float* Wz = (const float*)d_in[3];
  const float* Uz = (const float*)d_in[4];
  const float* Wr = (const float*)d_in[5];
  const float* Ur = (const float*)d_in[6];
  const float* bb = (const float*)d_in[7];
  const float* bz = (const float*)d_in[8];
  const float* br = (const float*)d_in[9];
  float* out = (float*)d_out;

  char* ws = (char*)d_ws;
  ushort_t* B1t   = (ushort_t*)(ws);                  // 6291456 B
  ushort_t* B2t   = (ushort_t*)(ws + 6291456);        // 3145728 B
  ushort_t* hb    = (ushort_t*)(ws + 9437184);        // 524288 B
  ushort_t* rhb   = (ushort_t*)(ws + 9961472);        // 524288 B
  float*    hf    = (float*)   (ws + 10485760);       // 1048576 B
  float*    zfb   = (float*)   (ws + 11534336);       // 1048576 B
  unsigned* flags = (unsigned*)(ws + 12582912);       // 4096 B
  ushort_t* xbf   = (ushort_t*)(ws + 12587008);       // 134217728 B -> end 146804736

  const int useXbf = (ws_size >= (size_t)146804736) ? 1 : 0;

  hipLaunchKernelGGL(repack_weights, dim3(24, 32, 2), dim3(256), 0, stream,
                     U, W, Uz, Wz, Ur, Wr, B1t, B2t);
  hipLaunchKernelGGL(init_state, dim3(1024), dim3(256), 0, stream, hb, hf, flags);
  if (useXbf) {
    hipLaunchKernelGGL(xconvert, dim3(32768), dim3(256), 0, stream, x, xbf);
  }
  hipLaunchKernelGGL(gru_persistent2, dim3(NBLK), dim3(256), 0, stream,
                     x, xbf, useXbf, B1t, B2t, hb, rhb, hf, zfb,
                     bb, bz, br, flags, out);
}

// Round 6
// 39174.991 us; speedup vs baseline: 1.0268x; 1.0268x over previous
//
#include <hip/hip_runtime.h>

typedef unsigned short ushort_t;
typedef __attribute__((ext_vector_type(8))) short short8;
typedef __attribute__((ext_vector_type(4))) float f32x4;
typedef __attribute__((ext_vector_type(4))) int i32x4;

#define NB   256     // batch
#define NT   512     // timesteps
#define ND   512     // input dim
#define NH   1024    // hidden dim
#define KK   1536    // NH + ND (fallback path concat K)
#define BK   128

// fast-path geometry
#define GROUPS      8    // independent batch groups (g = bid & 7 -> XCD-aligned)
#define ROWS_PER_G  32
#define BLKS_PER_G  64   // slots per group
#define NBLK        512  // 2 blocks/CU
#define KSR         8    // K-steps of 32 per wave (K=1024, 4-way K-split)

__device__ __forceinline__ ushort_t f2bf(float f) {
  union { float f; unsigned u; } v; v.f = f;
  unsigned u = v.u;
  return (ushort_t)((u + 0x7FFFu + ((u >> 16) & 1u)) >> 16);
}
__device__ __forceinline__ int pack2(float a, float b) {
  return (int)(((unsigned)f2bf(b) << 16) | (unsigned)f2bf(a));
}
__device__ __forceinline__ float bf2f(ushort_t h) {
  union { unsigned u; float f; } v; v.u = ((unsigned)h) << 16; return v.f;
}
__device__ __forceinline__ float sigmoidf_(float x) {
  return 1.f / (1.f + __expf(-x));
}
__device__ __forceinline__ float tanhf_(float x) {
  return 1.f - 2.f / (__expf(2.f * x) + 1.f);
}

// ===========================================================================
// Generic transpose-repack: src f32 [K][1024] (k-major) -> dst bf16 [1024][K]
// (n-major, k-contiguous). grid (K/64, 16), 256 threads.
// ===========================================================================
__global__ void repackT(const float* __restrict__ src, ushort_t* __restrict__ dst,
                        int K) {
  __shared__ float tile[64][65];
  const int k0 = blockIdx.x * 64, n0 = blockIdx.y * 64;
  const int tid = threadIdx.x;
  for (int i = 0; i < 16; ++i) {
    int e = tid + i * 256;
    int r = e >> 6, c = e & 63;
    tile[r][c] = src[(size_t)(k0 + r) * 1024 + n0 + c];
  }
  __syncthreads();
  for (int i = 0; i < 2; ++i) {
    int cch = tid + i * 256;
    int nl = cch >> 3, kc = (cch & 7) * 8;
    ushort_t tmp[8];
#pragma unroll
    for (int j = 0; j < 8; ++j) tmp[j] = f2bf(tile[kc + j][nl]);
    *reinterpret_cast<i32x4*>(dst + (size_t)(n0 + nl) * K + k0 + kc) =
        *reinterpret_cast<i32x4*>(tmp);
  }
}

__global__ void init_fast(ushort_t* __restrict__ hb, float* __restrict__ hf,
                          unsigned* __restrict__ flags) {
  int i = blockIdx.x * 256 + threadIdx.x;
  if (i < NB * NH) { hb[i] = 0; hf[i] = 0.f; }
  if (i < GROUPS * BLKS_PER_G) flags[i] = 0u;
}

// ===========================================================================
// Gx precompute: Gx[t*256+b][j] = bf16( x[b][t][:] @ Wcat[:,j] + bias[j] )
//   j: 0..1023 = z (Wz,bz), 1024..2047 = r (Wr,br), 2048..3071 = cand (W,bb)
// Bx: bf16 [3072][512] n-major. grid (2048, 48), 256 thr, 64x64 tile, K=512.
// ===========================================================================
__global__ void __launch_bounds__(256)
gxgemm(const float* __restrict__ x, const ushort_t* __restrict__ Bx,
       const float* __restrict__ bz, const float* __restrict__ br,
       const float* __restrict__ bb, ushort_t* __restrict__ Gx) {
  __shared__ __align__(16) char smem[32768];
  const int tid  = threadIdx.x;
  const int m0   = blockIdx.x * 64;
  const int n0   = blockIdx.y * 64;
  const int lane = tid & 63;
  const int w    = tid >> 6;
  const int wm   = w >> 1, wn = w & 1;
  const int l15  = lane & 15, l4 = lane >> 4;

  f32x4 acc[2][2];
#pragma unroll
  for (int i = 0; i < 2; ++i)
#pragma unroll
    for (int j = 0; j < 2; ++j) acc[i][j] = (f32x4){0.f, 0.f, 0.f, 0.f};

  for (int kb = 0; kb < 4; ++kb) {
    const int kbase = kb * BK;
    // stage A: 64 rows x 128 k, pack f32->bf16. 1024 chunks, 4/thread.
#pragma unroll
    for (int i = 0; i < 4; ++i) {
      int c = tid + (i << 8);
      int r = c >> 4, kc = (c & 15) << 3;
      int m = m0 + r;
      int tt = m >> 8, b = m & 255;
      const float* xp = x + ((size_t)b * NT + tt) * ND + kbase + kc;
      f32x4 f0 = *reinterpret_cast<const f32x4*>(xp);
      f32x4 f1 = *reinterpret_cast<const f32x4*>(xp + 4);
      i32x4 v;
      v[0] = pack2(f0[0], f0[1]); v[1] = pack2(f0[2], f0[3]);
      v[2] = pack2(f1[0], f1[1]); v[3] = pack2(f1[2], f1[3]);
      int off = (r << 8) + (((kc << 1)) ^ ((r & 7) << 4));
      *reinterpret_cast<i32x4*>(&smem[off]) = v;
    }
    // stage B: 64 cols x 128 k from Bx. 4/thread.
#pragma unroll
    for (int i = 0; i < 4; ++i) {
      int c = tid + (i << 8);
      int n = c >> 4, kc = (c & 15) << 3;
      i32x4 v = *reinterpret_cast<const i32x4*>(Bx + (size_t)(n0 + n) * 512 + kbase + kc);
      int off = 16384 + (n << 8) + (((kc << 1)) ^ ((n & 7) << 4));
      *reinterpret_cast<i32x4*>(&smem[off]) = v;
    }
    __syncthreads();
#pragma unroll
    for (int ks = 0; ks < 4; ++ks) {
      int kbyte = ks * 64 + l4 * 16;
      short8 a[2], b[2];
#pragma unroll
      for (int i = 0; i < 2; ++i) {
        int ra = wm * 32 + i * 16 + l15;
        a[i] = *reinterpret_cast<short8*>(&smem[(ra << 8) + (kbyte ^ ((ra & 7) << 4))]);
        int nb = wn * 32 + i * 16 + l15;
        b[i] = *reinterpret_cast<short8*>(&smem[16384 + (nb << 8) + (kbyte ^ ((nb & 7) << 4))]);
      }
#pragma unroll
      for (int i = 0; i < 2; ++i)
#pragma unroll
        for (int j = 0; j < 2; ++j)
          acc[i][j] = __builtin_amdgcn_mfma_f32_16x16x32_bf16(a[i], b[j], acc[i][j], 0, 0, 0);
    }
    __syncthreads();
  }
  // epilogue: + bias, -> bf16
#pragma unroll
  for (int i = 0; i < 2; ++i)
#pragma unroll
    for (int j = 0; j < 2; ++j) {
      int col = n0 + wn * 32 + j * 16 + l15;
      float bias = (col < NH) ? bz[col] : (col < 2 * NH ? br[col - NH] : bb[col - 2 * NH]);
      int mr = m0 + wm * 32 + i * 16 + 4 * l4;
#pragma unroll
      for (int jj = 0; jj < 4; ++jj)
        Gx[(size_t)(mr + jj) * 3072 + col] = f2bf(acc[i][j][jj] + bias);
    }
}

// ---------------------------------------------------------------------------
// Group barrier (proven in rounds 4/5): flag-array, agent scope.
// ---------------------------------------------------------------------------
__device__ __forceinline__ void group_barrier(unsigned* flags, int g, int slot,
                                              unsigned target, int tid) {
  __syncthreads();
  if (tid == 0) {
    __hip_atomic_store(flags + g * BLKS_PER_G + slot, target,
                       __ATOMIC_RELEASE, __HIP_MEMORY_SCOPE_AGENT);
  }
  if (tid < BLKS_PER_G) {
    while (__hip_atomic_load(flags + g * BLKS_PER_G + tid,
                             __ATOMIC_RELAXED, __HIP_MEMORY_SCOPE_AGENT) < target) {
      __builtin_amdgcn_s_sleep(4);
    }
  }
  __syncthreads();
  __builtin_amdgcn_fence(__ATOMIC_ACQUIRE, "agent");
}

// ===========================================================================
// Persistent GRU v3. 512 blocks x 256 threads (2 blocks/CU, 8 waves/CU).
// g = bid&7 (XCD-aligned group, 32 batch rows), slot = bid>>3 (64 per group).
// phase1: h @ [Uz|Ur] cols slot*32..+31 (of 2048), K=1024, 4-way wave K-split.
// phase2: (r*h) @ U cols slot*16..+15 (of 1024).
// Weights stationary in VGPRs: 24 short8 = 96 regs/thread (fits, no spill).
// Gx (x-projections + biases) precomputed; prefetched before each K-loop.
// ===========================================================================
__global__ void __launch_bounds__(256, 2)
gru_v3(const ushort_t* __restrict__ Gx,
       const ushort_t* __restrict__ Bu1, const ushort_t* __restrict__ Bu2,
       ushort_t* __restrict__ hb, ushort_t* __restrict__ rhb,
       float* __restrict__ hf, float* __restrict__ zfb,
       unsigned* __restrict__ flags, float* __restrict__ out) {
  __shared__ __align__(16) f32x4 redbuf[1024];   // 16KB

  const int tid  = threadIdx.x;
  const int bid  = blockIdx.x;
  const int w    = tid >> 6;
  const int lane = tid & 63;
  const int l15  = lane & 15;
  const int l4   = lane >> 4;
  const int g    = bid & 7;
  const int slot = bid >> 3;
  const int n1g  = slot * 32;            // phase1 col base (0..2047)
  const int n2g  = slot * 16;            // phase2 col base (0..1023)
  const int rowbase = g * ROWS_PER_G;
  const int kw   = w * 256 + 8 * l4;     // per-lane k base (K=1024 split 4 ways)

  // ---- stationary weights in registers: 96 VGPR ----
  short8 B1R[2][KSR];
  short8 B2R[KSR];
#pragma unroll
  for (int s = 0; s < KSR; ++s) {
    int k = kw + 32 * s;
#pragma unroll
    for (int j = 0; j < 2; ++j)
      B1R[j][s] = *reinterpret_cast<const short8*>(Bu1 + (size_t)(n1g + 16 * j + l15) * NH + k);
    B2R[s] = *reinterpret_cast<const short8*>(Bu2 + (size_t)(n2g + l15) * NH + k);
  }

  // ---- fixed per-thread epilogue coordinates ----
  const int col1 = n1g + (w & 1) * 16 + l15;       // phase1 tile (i=w>>1, j=w&1)
  const int r0_1 = rowbase + 16 * (w >> 1) + 4 * l4;
  const int col2 = n2g + l15;                      // phase2 (waves 0,1)
  const int r0_2 = rowbase + 16 * (w & 1) + 4 * l4;
  const bool zside = (col1 < NH);                  // block-uniform (slot<32)

  // ---- A-row base pointers ----
  const ushort_t* hbrow0 = hb  + (size_t)(rowbase + l15) * NH;
  const ushort_t* hbrow1 = hb  + (size_t)(rowbase + 16 + l15) * NH;
  const ushort_t* rhrow0 = rhb + (size_t)(rowbase + l15) * NH;
  const ushort_t* rhrow1 = rhb + (size_t)(rowbase + 16 + l15) * NH;

  unsigned epoch = 0;

  for (int t = 0; t < NT; ++t) {
    const size_t gxbase = (size_t)t * NB * 3072;

    // ================= phase 1: z | r =================
    float gx1[4], hfpre[4];
#pragma unroll
    for (int jj = 0; jj < 4; ++jj)
      gx1[jj] = bf2f(Gx[gxbase + (size_t)(r0_1 + jj) * 3072 + col1]);
    if (!zside) {
      int cc = col1 - NH;
#pragma unroll
      for (int jj = 0; jj < 4; ++jj)
        hfpre[jj] = hf[(size_t)(r0_1 + jj) * NH + cc];
    }

    f32x4 acc[2][2];
#pragma unroll
    for (int i = 0; i < 2; ++i)
#pragma unroll
      for (int j = 0; j < 2; ++j) acc[i][j] = (f32x4){0.f, 0.f, 0.f, 0.f};

#pragma unroll
    for (int s = 0; s < KSR; ++s) {
      int k = kw + 32 * s;
      short8 a0 = *reinterpret_cast<const short8*>(hbrow0 + k);
      short8 a1 = *reinterpret_cast<const short8*>(hbrow1 + k);
      acc[0][0] = __builtin_amdgcn_mfma_f32_16x16x32_bf16(a0, B1R[0][s], acc[0][0], 0, 0, 0);
      acc[0][1] = __builtin_amdgcn_mfma_f32_16x16x32_bf16(a0, B1R[1][s], acc[0][1], 0, 0, 0);
      acc[1][0] = __builtin_amdgcn_mfma_f32_16x16x32_bf16(a1, B1R[0][s], acc[1][0], 0, 0, 0);
      acc[1][1] = __builtin_amdgcn_mfma_f32_16x16x32_bf16(a1, B1R[1][s], acc[1][1], 0, 0, 0);
    }

    // ---- 4-way K-split reduction: dump 16 tiles, wave w reduces tile w ----
#pragma unroll
    for (int i = 0; i < 2; ++i)
#pragma unroll
      for (int j = 0; j < 2; ++j)
        redbuf[(w * 4 + i * 2 + j) * 64 + lane] = acc[i][j];
    __syncthreads();
    {
      f32x4 v = redbuf[(0 * 4 + w) * 64 + lane];
      v += redbuf[(1 * 4 + w) * 64 + lane];
      v += redbuf[(2 * 4 + w) * 64 + lane];
      v += redbuf[(3 * 4 + w) * 64 + lane];
      if (zside) {
#pragma unroll
        for (int jj = 0; jj < 4; ++jj)
          zfb[(size_t)(r0_1 + jj) * NH + col1] = sigmoidf_(v[jj] + gx1[jj]);
      } else {
        int cc = col1 - NH;
#pragma unroll
        for (int jj = 0; jj < 4; ++jj) {
          float rv = sigmoidf_(v[jj] + gx1[jj]);
          rhb[(size_t)(r0_1 + jj) * NH + cc] = f2bf(rv * hfpre[jj]);
        }
      }
    }
    group_barrier(flags, g, slot, ++epoch, tid);

    // ================= phase 2: h_cand + update =================
    float zpre[4], hf2[4], gxc[4];
    if (w < 2) {
#pragma unroll
      for (int jj = 0; jj < 4; ++jj) {
        size_t idx = (size_t)(r0_2 + jj) * NH + col2;
        zpre[jj] = zfb[idx];
        hf2[jj]  = hf[idx];
        gxc[jj]  = bf2f(Gx[gxbase + (size_t)(r0_2 + jj) * 3072 + 2048 + col2]);
      }
    }

    f32x4 acc2[2];
    acc2[0] = (f32x4){0.f, 0.f, 0.f, 0.f};
    acc2[1] = (f32x4){0.f, 0.f, 0.f, 0.f};
#pragma unroll
    for (int s = 0; s < KSR; ++s) {
      int k = kw + 32 * s;
      short8 a0 = *reinterpret_cast<const short8*>(rhrow0 + k);
      short8 a1 = *reinterpret_cast<const short8*>(rhrow1 + k);
      acc2[0] = __builtin_amdgcn_mfma_f32_16x16x32_bf16(a0, B2R[s], acc2[0], 0, 0, 0);
      acc2[1] = __builtin_amdgcn_mfma_f32_16x16x32_bf16(a1, B2R[s], acc2[1], 0, 0, 0);
    }
#pragma unroll
    for (int i = 0; i < 2; ++i)
      redbuf[(w * 2 + i) * 64 + lane] = acc2[i];
    __syncthreads();
    if (w < 2) {
      f32x4 v = redbuf[(0 * 2 + w) * 64 + lane];
      v += redbuf[(1 * 2 + w) * 64 + lane];
      v += redbuf[(2 * 2 + w) * 64 + lane];
      v += redbuf[(3 * 2 + w) * 64 + lane];
#pragma unroll
      for (int jj = 0; jj < 4; ++jj) {
        size_t idx = (size_t)(r0_2 + jj) * NH + col2;
        float hc = tanhf_(v[jj] + gxc[jj]);
        float zv = zpre[jj];
        float hn = (1.f - zv) * hf2[jj] + zv * hc;
        hf[idx] = hn;
        hb[idx] = f2bf(hn);
        if (t == NT - 1) out[idx] = hn;
      }
    }
    group_barrier(flags, g, slot, ++epoch, tid);
  }
}

// ===========================================================================
// ============== FALLBACK (round-2, proven): per-step launches ==============
// ===========================================================================
__global__ void repack_weights(const float* __restrict__ U,  const float* __restrict__ W,
                               const float* __restrict__ Uz, const float* __restrict__ Wz,
                               const float* __restrict__ Ur, const float* __restrict__ Wr,
                               ushort_t* __restrict__ B1t, ushort_t* __restrict__ B2t) {
  const int kt = blockIdx.x, nt = blockIdx.y, which = blockIdx.z;
  if (which == 1 && nt >= 16) return;
  __shared__ float tile[64][65];
  const int k0 = kt * 64, n0 = nt * 64;
  const int tid = threadIdx.x;
  for (int i = 0; i < 16; ++i) {
    int e = tid + i * 256;
    int r = e >> 6, c = e & 63;
    int k = k0 + r, n = n0 + c;
    int nn = n & 1023;
    const float* src;
    if (which == 0) {
      if (k < NH) src = (n < NH ? Uz : Ur) + (size_t)k * NH + nn;
      else        src = (n < NH ? Wz : Wr) + (size_t)(k - NH) * NH + nn;
    } else {
      if (k < NH) src = U + (size_t)k * NH + nn;
      else        src = W + (size_t)(k - NH) * NH + nn;
    }
    tile[r][c] = *src;
  }
  __syncthreads();
  ushort_t* dst = (which == 0) ? B1t : B2t;
  for (int i = 0; i < 2; ++i) {
    int cch = tid + i * 256;
    int nl = cch >> 3, kc = (cch & 7) * 8;
    ushort_t tmp[8];
#pragma unroll
    for (int j = 0; j < 8; ++j) tmp[j] = f2bf(tile[kc + j][nl]);
    *reinterpret_cast<i32x4*>(dst + (size_t)(n0 + nl) * KK + k0 + kc) =
        *reinterpret_cast<i32x4*>(tmp);
  }
}

__global__ void init_state(ushort_t* __restrict__ hb, float* __restrict__ hf) {
  int i = blockIdx.x * 256 + threadIdx.x;
  if (i < NB * NH) { hb[i] = 0; hf[i] = 0.f; }
}

__global__ void __launch_bounds__(256)
gru_phase1(const float* __restrict__ x, const ushort_t* __restrict__ B1t,
           const ushort_t* __restrict__ hb, ushort_t* __restrict__ rhb,
           const float* __restrict__ hf, float* __restrict__ zfb,
           const float* __restrict__ bz, const float* __restrict__ br, int t) {
  __shared__ __align__(16) char smem[24576];
  const int tid  = threadIdx.x;
  const int bid  = blockIdx.x;
  const int lane = tid & 63;
  const int w    = tid >> 6;
  const int wm   = w >> 1, wn = w & 1;
  const int m0   = (bid >> 5) * 32;
  const int n1   = (bid & 31) * 64;
  const int l15  = lane & 15, l4 = lane >> 4;

  f32x4 acc0 = {0.f, 0.f, 0.f, 0.f}, acc1 = {0.f, 0.f, 0.f, 0.f};
  for (int kb = 0; kb < KK / BK; ++kb) {
    const int kbase = kb * BK;
#pragma unroll
    for (int i = 0; i < 2; ++i) {
      int c = tid + (i << 8);
      int r = c >> 4, kc = (c & 15) << 3;
      int m = m0 + r, k = kbase + kc;
      i32x4 v;
      if (k < NH) {
        v = *reinterpret_cast<const i32x4*>(hb + (size_t)m * NH + k);
      } else {
        const float* xp = x + (size_t)m * (NT * ND) + (size_t)t * ND + (k - NH);
        f32x4 f0 = *reinterpret_cast<const f32x4*>(xp);
        f32x4 f1 = *reinterpret_cast<const f32x4*>(xp + 4);
        v[0] = pack2(f0[0], f0[1]); v[1] = pack2(f0[2], f0[3]);
        v[2] = pack2(f1[0], f1[1]); v[3] = pack2(f1[2], f1[3]);
      }
      int off = (r << 8) + (((kc << 1)) ^ ((r & 7) << 4));
      *reinterpret_cast<i32x4*>(&smem[off]) = v;
    }
#pragma unroll
    for (int i = 0; i < 4; ++i) {
      int c = tid + (i << 8);
      int n = c >> 4, kc = (c & 15) << 3;
      i32x4 v = *reinterpret_cast<const i32x4*>(B1t + (size_t)(n1 + n) * KK + kbase + kc);
      int off = 8192 + (n << 8) + (((kc << 1)) ^ ((n & 7) << 4));
      *reinterpret_cast<i32x4*>(&smem[off]) = v;
    }
    __syncthreads();
#pragma unroll
    for (int ks = 0; ks < 4; ++ks) {
      int kbyte = ks * 64 + l4 * 16;
      int ra = wm * 16 + l15;
      short8 a = *reinterpret_cast<short8*>(&smem[(ra << 8) + (kbyte ^ ((ra & 7) << 4))]);
      int nb0 = wn * 32 + l15;
      short8 b0 = *reinterpret_cast<short8*>(&smem[8192 + (nb0 << 8) + (kbyte ^ ((nb0 & 7) << 4))]);
      int nb1 = nb0 + 16;
      short8 b1 = *reinterpret_cast<short8*>(&smem[8192 + (nb1 << 8) + (kbyte ^ ((nb1 & 7) << 4))]);
      acc0 = __builtin_amdgcn_mfma_f32_16x16x32_bf16(a, b0, acc0, 0, 0, 0);
      acc1 = __builtin_amdgcn_mfma_f32_16x16x32_bf16(a, b1, acc1, 0, 0, 0);
    }
    __syncthreads();
  }
  int mrow = m0 + wm * 16 + l4 * 4;
#pragma unroll
  for (int f = 0; f < 2; ++f) {
    f32x4 av = f ? acc1 : acc0;
    int c = n1 + wn * 32 + f * 16 + l15;
#pragma unroll
    for (int j = 0; j < 4; ++j) {
      int m = mrow + j;
      float v = av[j];
      if (c < NH) {
        zfb[(size_t)m * NH + c] = sigmoidf_(v + bz[c]);
      } else {
        int cc = c - NH;
        float rv = sigmoidf_(v + br[cc]);
        rhb[(size_t)m * NH + cc] = f2bf(rv * hf[(size_t)m * NH + cc]);
      }
    }
  }
}

__global__ void __launch_bounds__(256)
gru_phase2(const float* __restrict__ x, const ushort_t* __restrict__ B2t,
           ushort_t* __restrict__ hb, const ushort_t* __restrict__ rhb,
           float* __restrict__ hf, const float* __restrict__ zfb,
           const float* __restrict__ bb, float* __restrict__ out, int t) {
  __shared__ __align__(16) char smem[16384];
  const int tid  = threadIdx.x;
  const int bid  = blockIdx.x;
  const int lane = tid & 63;
  const int w    = tid >> 6;
  const int wm   = w >> 1, wn = w & 1;
  const int m0   = (bid >> 5) * 32;
  const int n2   = (bid & 31) * 32;
  const int l15  = lane & 15, l4 = lane >> 4;

  f32x4 acc = {0.f, 0.f, 0.f, 0.f};
  for (int kb = 0; kb < KK / BK; ++kb) {
    const int kbase = kb * BK;
#pragma unroll
    for (int i = 0; i < 2; ++i) {
      int c = tid + (i << 8);
      int r = c >> 4, kc = (c & 15) << 3;
      int m = m0 + r, k = kbase + kc;
      i32x4 v;
      if (k < NH) {
        v = *reinterpret_cast<const i32x4*>(rhb + (size_t)m * NH + k);
      } else {
        const float* xp = x + (size_t)m * (NT * ND) + (size_t)t * ND + (k - NH);
        f32x4 f0 = *reinterpret_cast<const f32x4*>(xp);
        f32x4 f1 = *reinterpret_cast<const f32x4*>(xp + 4);
        v[0] = pack2(f0[0], f0[1]); v[1] = pack2(f0[2], f0[3]);
        v[2] = pack2(f1[0], f1[1]); v[3] = pack2(f1[2], f1[3]);
      }
      int off = (r << 8) + (((kc << 1)) ^ ((r & 7) << 4));
      *reinterpret_cast<i32x4*>(&smem[off]) = v;
    }
#pragma unroll
    for (int i = 0; i < 2; ++i) {
      int c = tid + (i << 8);
      int n = c >> 4, kc = (c & 15) << 3;
      i32x4 v = *reinterpret_cast<const i32x4*>(B2t + (size_t)(n2 + n) * KK + kbase + kc);
      int off = 8192 + (n << 8) + (((kc << 1)) ^ ((n & 7) << 4));
      *reinterpret_cast<i32x4*>(&smem[off]) = v;
    }
    __syncthreads();
#pragma unroll
    for (int ks = 0; ks < 4; ++ks) {
      int kbyte = ks * 64 + l4 * 16;
      int ra = wm * 16 + l15;
      short8 a = *reinterpret_cast<short8*>(&smem[(ra << 8) + (kbyte ^ ((ra & 7) << 4))]);
      int nb = wn * 16 + l15;
      short8 b0 = *reinterpret_cast<short8*>(&smem[8192 + (nb << 8) + (kbyte ^ ((nb & 7) << 4))]);
      acc = __builtin_amdgcn_mfma_f32_16x16x32_bf16(a, b0, acc, 0, 0, 0);
    }
    __syncthreads();
  }
  int mrow = m0 + wm * 16 + l4 * 4;
  int c = n2 + wn * 16 + l15;
#pragma unroll
  for (int j = 0; j < 4; ++j) {
    int m = mrow + j;
    size_t idx = (size_t)m * NH + c;
    float hc = tanhf_(acc[j] + bb[c]);
    float zv = zfb[idx];
    float hn = (1.f - zv) * hf[idx] + zv * hc;
    hf[idx] = hn;
    hb[idx] = f2bf(hn);
    if (t == NT - 1) out[idx] = hn;
  }
}

// ===========================================================================
extern "C" void kernel_launch(void* const* d_in, const int* in_sizes, int n_in,
                              void* d_out, int out_size, void* d_ws, size_t ws_size,
                              hipStream_t stream) {
  const float* x  = (const float*)d_in[0];
  const float* W  = (const float*)d_in[1];
  const float* U  = (const float*)d_in[2];
  const float* Wz = (const float*)d_in[3];
  const float* Uz = (const float*)d_in[4];
  const float* Wr = (const float*)d_in[5];
  const float* Ur = (const float*)d_in[6];
  const float* bb = (const float*)d_in[7];
  const float* bz = (const float*)d_in[8];
  const float* br = (const float*)d_in[9];
  float* out = (float*)d_out;
  char* ws = (char*)d_ws;

  // fast-path workspace layout
  ushort_t* Bu1   = (ushort_t*)(ws);                  //  4,194,304
  ushort_t* Bu2   = (ushort_t*)(ws + 4194304);        //  2,097,152
  ushort_t* Bx    = (ushort_t*)(ws + 6291456);        //  3,145,728
  ushort_t* hb    = (ushort_t*)(ws + 9437184);        //    524,288
  ushort_t* rhb   = (ushort_t*)(ws + 9961472);        //    524,288
  float*    hf    = (float*)   (ws + 10485760);       //  1,048,576
  float*    zfb   = (float*)   (ws + 11534336);       //  1,048,576
  unsigned* flags = (unsigned*)(ws + 12582912);       //      4,096
  ushort_t* Gx    = (ushort_t*)(ws + 12587008);       // 805,306,368 -> 817,893,376

  const bool fast = (ws_size >= (size_t)817893376ULL);

  if (fast) {
    // repack recurrent + input weights (n-major bf16)
    hipLaunchKernelGGL(repackT, dim3(16, 16), dim3(256), 0, stream, Uz, Bu1, NH);
    hipLaunchKernelGGL(repackT, dim3(16, 16), dim3(256), 0, stream, Ur, Bu1 + (size_t)NH * NH, NH);
    hipLaunchKernelGGL(repackT, dim3(16, 16), dim3(256), 0, stream, U,  Bu2, NH);
    hipLaunchKernelGGL(repackT, dim3(8, 16),  dim3(256), 0, stream, Wz, Bx, ND);
    hipLaunchKernelGGL(repackT, dim3(8, 16),  dim3(256), 0, stream, Wr, Bx + (size_t)NH * ND, ND);
    hipLaunchKernelGGL(repackT, dim3(8, 16),  dim3(256), 0, stream, W,  Bx + (size_t)2 * NH * ND, ND);
    hipLaunchKernelGGL(init_fast, dim3(1024), dim3(256), 0, stream, hb, hf, flags);
    // Gx = x @ [Wz|Wr|W] + [bz|br|bb]
    hipLaunchKernelGGL(gxgemm, dim3(2048, 48), dim3(256), 0, stream, x, Bx, bz, br, bb, Gx);
    // persistent recurrence
    hipLaunchKernelGGL(gru_v3, dim3(NBLK), dim3(256), 0, stream,
                       Gx, Bu1, Bu2, hb, rhb, hf, zfb, flags, out);
  } else {
    // fallback: proven round-2 per-step path
    ushort_t* B1t  = (ushort_t*)(ws);                  // 6,291,456
    ushort_t* B2t  = (ushort_t*)(ws + 6291456);        // 3,145,728
    ushort_t* hb2  = (ushort_t*)(ws + 9437184);
    ushort_t* rhb2 = (ushort_t*)(ws + 9961472);
    float*    hf2  = (float*)   (ws + 10485760);
    float*    zfb2 = (float*)   (ws + 11534336);
    hipLaunchKernelGGL(repack_weights, dim3(24, 32, 2), dim3(256), 0, stream,
                       U, W, Uz, Wz, Ur, Wr, B1t, B2t);
    hipLaunchKernelGGL(init_state, dim3(1024), dim3(256), 0, stream, hb2, hf2);
    for (int t = 0; t < NT; ++t) {
      hipLaunchKernelGGL(gru_phase1, dim3(256), dim3(256), 0, stream,
                         x, B1t, hb2, rhb2, hf2, zfb2, bz, br, t);
      hipLaunchKernelGGL(gru_phase2, dim3(256), dim3(256), 0, stream,
                         x, B2t, hb2, rhb2, hf2, zfb2, bb, out, t);
    }
  }
}

// Round 7
// 22490.526 us; speedup vs baseline: 1.7885x; 1.7418x over previous
//
#include <hip/hip_runtime.h>

typedef unsigned short ushort_t;
typedef __attribute__((ext_vector_type(8))) short short8;
typedef __attribute__((ext_vector_type(4))) float f32x4;
typedef __attribute__((ext_vector_type(4))) int i32x4;

#define NB   256     // batch
#define NT   512     // timesteps
#define ND   512     // input dim
#define NH   1024    // hidden dim
#define KK   1536    // NH + ND (fallback path concat K)
#define BK   128

// fast-path geometry
#define GROUPS      4    // independent batch groups
#define ROWS_PER_G  64
#define BLKS_PER_G  64   // blocks per group
#define NBLK        256  // 1 block/CU, 512 threads

__device__ __forceinline__ ushort_t f2bf(float f) {
  union { float f; unsigned u; } v; v.f = f;
  unsigned u = v.u;
  return (ushort_t)((u + 0x7FFFu + ((u >> 16) & 1u)) >> 16);
}
__device__ __forceinline__ int pack2(float a, float b) {
  return (int)(((unsigned)f2bf(b) << 16) | (unsigned)f2bf(a));
}
__device__ __forceinline__ float bf2f(ushort_t h) {
  union { unsigned u; float f; } v; v.u = ((unsigned)h) << 16; return v.f;
}
__device__ __forceinline__ float sigmoidf_(float x) {
  return 1.f / (1.f + __expf(-x));
}
__device__ __forceinline__ float tanhf_(float x) {
  return 1.f - 2.f / (__expf(2.f * x) + 1.f);
}

// ===========================================================================
// Transpose-repack: src f32 [K][1024] -> dst bf16 [1024][K] (n-major).
// ===========================================================================
__global__ void repackT(const float* __restrict__ src, ushort_t* __restrict__ dst,
                        int K) {
  __shared__ float tile[64][65];
  const int k0 = blockIdx.x * 64, n0 = blockIdx.y * 64;
  const int tid = threadIdx.x;
  for (int i = 0; i < 16; ++i) {
    int e = tid + i * 256;
    int r = e >> 6, c = e & 63;
    tile[r][c] = src[(size_t)(k0 + r) * 1024 + n0 + c];
  }
  __syncthreads();
  for (int i = 0; i < 2; ++i) {
    int cch = tid + i * 256;
    int nl = cch >> 3, kc = (cch & 7) * 8;
    ushort_t tmp[8];
#pragma unroll
    for (int j = 0; j < 8; ++j) tmp[j] = f2bf(tile[kc + j][nl]);
    *reinterpret_cast<i32x4*>(dst + (size_t)(n0 + nl) * K + k0 + kc) =
        *reinterpret_cast<i32x4*>(tmp);
  }
}

__global__ void init_fast(ushort_t* __restrict__ hb, float* __restrict__ hf,
                          unsigned* __restrict__ flags) {
  int i = blockIdx.x * 256 + threadIdx.x;
  if (i < NB * NH) { hb[i] = 0; hf[i] = 0.f; }
  if (i < GROUPS * 16) flags[i] = 0u;
}

// ===========================================================================
// Gx precompute (verified round 6): Gx[t*256+b][j], j: 0..1023=z, 1024..2047=r,
// 2048..3071=cand. Bx bf16 [3072][512] n-major.
// ===========================================================================
__global__ void __launch_bounds__(256)
gxgemm(const float* __restrict__ x, const ushort_t* __restrict__ Bx,
       const float* __restrict__ bz, const float* __restrict__ br,
       const float* __restrict__ bb, ushort_t* __restrict__ Gx) {
  __shared__ __align__(16) char smem[32768];
  const int tid  = threadIdx.x;
  const int m0   = blockIdx.x * 64;
  const int n0   = blockIdx.y * 64;
  const int lane = tid & 63;
  const int w    = tid >> 6;
  const int wm   = w >> 1, wn = w & 1;
  const int l15  = lane & 15, l4 = lane >> 4;

  f32x4 acc[2][2];
#pragma unroll
  for (int i = 0; i < 2; ++i)
#pragma unroll
    for (int j = 0; j < 2; ++j) acc[i][j] = (f32x4){0.f, 0.f, 0.f, 0.f};

  for (int kb = 0; kb < 4; ++kb) {
    const int kbase = kb * BK;
#pragma unroll
    for (int i = 0; i < 4; ++i) {
      int c = tid + (i << 8);
      int r = c >> 4, kc = (c & 15) << 3;
      int m = m0 + r;
      int tt = m >> 8, b = m & 255;
      const float* xp = x + ((size_t)b * NT + tt) * ND + kbase + kc;
      f32x4 f0 = *reinterpret_cast<const f32x4*>(xp);
      f32x4 f1 = *reinterpret_cast<const f32x4*>(xp + 4);
      i32x4 v;
      v[0] = pack2(f0[0], f0[1]); v[1] = pack2(f0[2], f0[3]);
      v[2] = pack2(f1[0], f1[1]); v[3] = pack2(f1[2], f1[3]);
      int off = (r << 8) + (((kc << 1)) ^ ((r & 7) << 4));
      *reinterpret_cast<i32x4*>(&smem[off]) = v;
    }
#pragma unroll
    for (int i = 0; i < 4; ++i) {
      int c = tid + (i << 8);
      int n = c >> 4, kc = (c & 15) << 3;
      i32x4 v = *reinterpret_cast<const i32x4*>(Bx + (size_t)(n0 + n) * 512 + kbase + kc);
      int off = 16384 + (n << 8) + (((kc << 1)) ^ ((n & 7) << 4));
      *reinterpret_cast<i32x4*>(&smem[off]) = v;
    }
    __syncthreads();
#pragma unroll
    for (int ks = 0; ks < 4; ++ks) {
      int kbyte = ks * 64 + l4 * 16;
      short8 a[2], b[2];
#pragma unroll
      for (int i = 0; i < 2; ++i) {
        int ra = wm * 32 + i * 16 + l15;
        a[i] = *reinterpret_cast<short8*>(&smem[(ra << 8) + (kbyte ^ ((ra & 7) << 4))]);
        int nb = wn * 32 + i * 16 + l15;
        b[i] = *reinterpret_cast<short8*>(&smem[16384 + (nb << 8) + (kbyte ^ ((nb & 7) << 4))]);
      }
#pragma unroll
      for (int i = 0; i < 2; ++i)
#pragma unroll
        for (int j = 0; j < 2; ++j)
          acc[i][j] = __builtin_amdgcn_mfma_f32_16x16x32_bf16(a[i], b[j], acc[i][j], 0, 0, 0);
    }
    __syncthreads();
  }
#pragma unroll
  for (int i = 0; i < 2; ++i)
#pragma unroll
    for (int j = 0; j < 2; ++j) {
      int col = n0 + wn * 32 + j * 16 + l15;
      float bias = (col < NH) ? bz[col] : (col < 2 * NH ? br[col - NH] : bb[col - 2 * NH]);
      int mr = m0 + wm * 32 + i * 16 + 4 * l4;
#pragma unroll
      for (int jj = 0; jj < 4; ++jj)
        Gx[(size_t)(mr + jj) * 3072 + col] = f2bf(acc[i][j][jj] + bias);
    }
}

// ---------------------------------------------------------------------------
// Group barrier v2: atomicAdd arrival counter + single generation word.
// Monotonic epochs, no counter reset. Release fence before arrival,
// acquire fence after observing generation.
// ---------------------------------------------------------------------------
__device__ __forceinline__ void group_barrier2(unsigned* flags, int g,
                                               unsigned epoch, int tid) {
  __syncthreads();
  if (tid == 0) {
    unsigned* ctr = flags + g * 16;
    unsigned* gen = flags + g * 16 + 8;
    __builtin_amdgcn_fence(__ATOMIC_RELEASE, "agent");
    unsigned old = __hip_atomic_fetch_add(ctr, 1u, __ATOMIC_RELAXED,
                                          __HIP_MEMORY_SCOPE_AGENT);
    if (old == (unsigned)BLKS_PER_G * epoch - 1u) {
      __hip_atomic_store(gen, epoch, __ATOMIC_RELEASE, __HIP_MEMORY_SCOPE_AGENT);
    }
    while (__hip_atomic_load(gen, __ATOMIC_RELAXED, __HIP_MEMORY_SCOPE_AGENT) < epoch) {
      __builtin_amdgcn_s_sleep(1);
    }
    __builtin_amdgcn_fence(__ATOMIC_ACQUIRE, "agent");
  }
  __syncthreads();
}

// ===========================================================================
// Persistent GRU v4: weights stationary in LDS (96KB dynamic), tiny registers.
// 256 blocks x 512 threads (1 block/CU, 8 waves). g=bid>>6, slot=bid&63.
// phase1: wave (mt=w>>1, ct=w&1): rows 16mt..+15, cols n1g+16ct..+15, K=1024
//         -> 32 MFMAs, acc=4 VGPRs, no cross-wave reduction.
// phase2: waves 0..3: rows 16w..+15, cols n2g..+15, K=1024.
// ===========================================================================
__global__ void __launch_bounds__(512, 1)
gru_v4(const ushort_t* __restrict__ Gx,
       const ushort_t* __restrict__ Bu1, const ushort_t* __restrict__ Bu2,
       ushort_t* __restrict__ hb, ushort_t* __restrict__ rhb,
       float* __restrict__ hf, float* __restrict__ zfb,
       unsigned* __restrict__ flags, float* __restrict__ out) {
  extern __shared__ __align__(16) char dsm[];   // 98304 B: B1 64KB | B2 32KB

  const int tid  = threadIdx.x;
  const int bid  = blockIdx.x;
  const int w    = tid >> 6;
  const int lane = tid & 63;
  const int l15  = lane & 15;
  const int l4   = lane >> 4;
  const int g    = bid >> 6;
  const int slot = bid & 63;
  const int n1g  = slot * 32;
  const int n2g  = slot * 16;
  const int rowbase = g * ROWS_PER_G;

  // ---- preload weight slices into LDS (once), swizzled ----
  for (int i = 0; i < 12; ++i) {
    int c = tid + i * 512;                 // 0..6143
    int isB2 = (c >= 4096) ? 1 : 0;
    int cc = c - (isB2 << 12);
    int cl = cc >> 7;                      // local col (B1:0..31, B2:0..15)
    int kc = (cc & 127) * 8;               // k element base
    const ushort_t* srcb = isB2
        ? Bu2 + (((size_t)(n2g + cl)) << 10) + kc
        : Bu1 + (((size_t)(n1g + cl)) << 10) + kc;
    i32x4 v = *reinterpret_cast<const i32x4*>(srcb);
    int off = (isB2 << 16) + (cl << 11) + ((kc << 1) ^ ((cl & 7) << 4));
    *reinterpret_cast<i32x4*>(&dsm[off]) = v;
  }
  __syncthreads();

  // ---- per-thread coordinates ----
  const int mt1  = w >> 1, ct1 = w & 1;
  const int col1 = n1g + ct1 * 16 + l15;
  const int r0_1 = rowbase + 16 * mt1 + 4 * l4;
  const bool zside = (slot < 32);
  const ushort_t* arow1 = hb + (size_t)(rowbase + 16 * mt1 + l15) * NH;
  const int b1base = (ct1 * 16 + l15) << 11;
  const int bswz   = (l15 & 7) << 4;

  const int col2 = n2g + l15;                       // phase2 (waves 0..3)
  const int r0_2 = rowbase + 16 * w + 4 * l4;
  const ushort_t* arow2 = rhb + (size_t)(rowbase + 16 * w + l15) * NH;
  const int b2base = 65536 + (l15 << 11);

  unsigned epoch = 0;

  for (int t = 0; t < NT; ++t) {
    const size_t gxbase = (size_t)t * NB * 3072;

    // ================= phase 1: z | r =================
    float gx1[4], hfpre[4];
#pragma unroll
    for (int jj = 0; jj < 4; ++jj)
      gx1[jj] = bf2f(Gx[gxbase + (size_t)(r0_1 + jj) * 3072 + col1]);
    if (!zside) {
      int cc = col1 - NH;
#pragma unroll
      for (int jj = 0; jj < 4; ++jj)
        hfpre[jj] = hf[(size_t)(r0_1 + jj) * NH + cc];
    }

    f32x4 acc = {0.f, 0.f, 0.f, 0.f};
#pragma unroll
    for (int s = 0; s < 32; ++s) {
      short8 a = *reinterpret_cast<const short8*>(arow1 + 8 * l4 + 32 * s);
      short8 b = *reinterpret_cast<const short8*>(
          &dsm[b1base + ((64 * s + 16 * l4) ^ bswz)]);
      acc = __builtin_amdgcn_mfma_f32_16x16x32_bf16(a, b, acc, 0, 0, 0);
    }
    if (zside) {
#pragma unroll
      for (int jj = 0; jj < 4; ++jj)
        zfb[(size_t)(r0_1 + jj) * NH + col1] = sigmoidf_(acc[jj] + gx1[jj]);
    } else {
      int cc = col1 - NH;
#pragma unroll
      for (int jj = 0; jj < 4; ++jj) {
        float rv = sigmoidf_(acc[jj] + gx1[jj]);
        rhb[(size_t)(r0_1 + jj) * NH + cc] = f2bf(rv * hfpre[jj]);
      }
    }

    // prefetch phase2 operands that do NOT depend on phase1 (hide under barrier)
    float gxc[4], hf2[4];
    if (w < 4) {
#pragma unroll
      for (int jj = 0; jj < 4; ++jj) {
        gxc[jj] = bf2f(Gx[gxbase + (size_t)(r0_2 + jj) * 3072 + 2048 + col2]);
        hf2[jj] = hf[(size_t)(r0_2 + jj) * NH + col2];
      }
    }

    ++epoch;
    group_barrier2(flags, g, epoch, tid);

    // ================= phase 2: h_cand + update =================
    if (w < 4) {
      float zpre[4];
#pragma unroll
      for (int jj = 0; jj < 4; ++jj)
        zpre[jj] = zfb[(size_t)(r0_2 + jj) * NH + col2];

      f32x4 acc2 = {0.f, 0.f, 0.f, 0.f};
#pragma unroll
      for (int s = 0; s < 32; ++s) {
        short8 a = *reinterpret_cast<const short8*>(arow2 + 8 * l4 + 32 * s);
        short8 b = *reinterpret_cast<const short8*>(
            &dsm[b2base + ((64 * s + 16 * l4) ^ bswz)]);
        acc2 = __builtin_amdgcn_mfma_f32_16x16x32_bf16(a, b, acc2, 0, 0, 0);
      }
#pragma unroll
      for (int jj = 0; jj < 4; ++jj) {
        size_t idx = (size_t)(r0_2 + jj) * NH + col2;
        float hc = tanhf_(acc2[jj] + gxc[jj]);
        float zv = zpre[jj];
        float hn = (1.f - zv) * hf2[jj] + zv * hc;
        hf[idx] = hn;
        hb[idx] = f2bf(hn);
        if (t == NT - 1) out[idx] = hn;
      }
    }
    ++epoch;
    group_barrier2(flags, g, epoch, tid);
  }
}

// ===========================================================================
// ============== FALLBACK (round-2, proven): per-step launches ==============
// ===========================================================================
__global__ void repack_weights(const float* __restrict__ U,  const float* __restrict__ W,
                               const float* __restrict__ Uz, const float* __restrict__ Wz,
                               const float* __restrict__ Ur, const float* __restrict__ Wr,
                               ushort_t* __restrict__ B1t, ushort_t* __restrict__ B2t) {
  const int kt = blockIdx.x, nt = blockIdx.y, which = blockIdx.z;
  if (which == 1 && nt >= 16) return;
  __shared__ float tile[64][65];
  const int k0 = kt * 64, n0 = nt * 64;
  const int tid = threadIdx.x;
  for (int i = 0; i < 16; ++i) {
    int e = tid + i * 256;
    int r = e >> 6, c = e & 63;
    int k = k0 + r, n = n0 + c;
    int nn = n & 1023;
    const float* src;
    if (which == 0) {
      if (k < NH) src = (n < NH ? Uz : Ur) + (size_t)k * NH + nn;
      else        src = (n < NH ? Wz : Wr) + (size_t)(k - NH) * NH + nn;
    } else {
      if (k < NH) src = U + (size_t)k * NH + nn;
      else        src = W + (size_t)(k - NH) * NH + nn;
    }
    tile[r][c] = *src;
  }
  __syncthreads();
  ushort_t* dst = (which == 0) ? B1t : B2t;
  for (int i = 0; i < 2; ++i) {
    int cch = tid + i * 256;
    int nl = cch >> 3, kc = (cch & 7) * 8;
    ushort_t tmp[8];
#pragma unroll
    for (int j = 0; j < 8; ++j) tmp[j] = f2bf(tile[kc + j][nl]);
    *reinterpret_cast<i32x4*>(dst + (size_t)(n0 + nl) * KK + k0 + kc) =
        *reinterpret_cast<i32x4*>(tmp);
  }
}

__global__ void init_state(ushort_t* __restrict__ hb, float* __restrict__ hf) {
  int i = blockIdx.x * 256 + threadIdx.x;
  if (i < NB * NH) { hb[i] = 0; hf[i] = 0.f; }
}

__global__ void __launch_bounds__(256)
gru_phase1(const float* __restrict__ x, const ushort_t* __restrict__ B1t,
           const ushort_t* __restrict__ hb, ushort_t* __restrict__ rhb,
           const float* __restrict__ hf, float* __restrict__ zfb,
           const float* __restrict__ bz, const float* __restrict__ br, int t) {
  __shared__ __align__(16) char smem[24576];
  const int tid  = threadIdx.x;
  const int bid  = blockIdx.x;
  const int lane = tid & 63;
  const int w    = tid >> 6;
  const int wm   = w >> 1, wn = w & 1;
  const int m0   = (bid >> 5) * 32;
  const int n1   = (bid & 31) * 64;
  const int l15  = lane & 15, l4 = lane >> 4;

  f32x4 acc0 = {0.f, 0.f, 0.f, 0.f}, acc1 = {0.f, 0.f, 0.f, 0.f};
  for (int kb = 0; kb < KK / BK; ++kb) {
    const int kbase = kb * BK;
#pragma unroll
    for (int i = 0; i < 2; ++i) {
      int c = tid + (i << 8);
      int r = c >> 4, kc = (c & 15) << 3;
      int m = m0 + r, k = kbase + kc;
      i32x4 v;
      if (k < NH) {
        v = *reinterpret_cast<const i32x4*>(hb + (size_t)m * NH + k);
      } else {
        const float* xp = x + (size_t)m * (NT * ND) + (size_t)t * ND + (k - NH);
        f32x4 f0 = *reinterpret_cast<const f32x4*>(xp);
        f32x4 f1 = *reinterpret_cast<const f32x4*>(xp + 4);
        v[0] = pack2(f0[0], f0[1]); v[1] = pack2(f0[2], f0[3]);
        v[2] = pack2(f1[0], f1[1]); v[3] = pack2(f1[2], f1[3]);
      }
      int off = (r << 8) + (((kc << 1)) ^ ((r & 7) << 4));
      *reinterpret_cast<i32x4*>(&smem[off]) = v;
    }
#pragma unroll
    for (int i = 0; i < 4; ++i) {
      int c = tid + (i << 8);
      int n = c >> 4, kc = (c & 15) << 3;
      i32x4 v = *reinterpret_cast<const i32x4*>(B1t + (size_t)(n1 + n) * KK + kbase + kc);
      int off = 8192 + (n << 8) + (((kc << 1)) ^ ((n & 7) << 4));
      *reinterpret_cast<i32x4*>(&smem[off]) = v;
    }
    __syncthreads();
#pragma unroll
    for (int ks = 0; ks < 4; ++ks) {
      int kbyte = ks * 64 + l4 * 16;
      int ra = wm * 16 + l15;
      short8 a = *reinterpret_cast<short8*>(&smem[(ra << 8) + (kbyte ^ ((ra & 7) << 4))]);
      int nb0 = wn * 32 + l15;
      short8 b0 = *reinterpret_cast<short8*>(&smem[8192 + (nb0 << 8) + (kbyte ^ ((nb0 & 7) << 4))]);
      int nb1 = nb0 + 16;
      short8 b1 = *reinterpret_cast<short8*>(&smem[8192 + (nb1 << 8) + (kbyte ^ ((nb1 & 7) << 4))]);
      acc0 = __builtin_amdgcn_mfma_f32_16x16x32_bf16(a, b0, acc0, 0, 0, 0);
      acc1 = __builtin_amdgcn_mfma_f32_16x16x32_bf16(a, b1, acc1, 0, 0, 0);
    }
    __syncthreads();
  }
  int mrow = m0 + wm * 16 + l4 * 4;
#pragma unroll
  for (int f = 0; f < 2; ++f) {
    f32x4 av = f ? acc1 : acc0;
    int c = n1 + wn * 32 + f * 16 + l15;
#pragma unroll
    for (int j = 0; j < 4; ++j) {
      int m = mrow + j;
      float v = av[j];
      if (c < NH) {
        zfb[(size_t)m * NH + c] = sigmoidf_(v + bz[c]);
      } else {
        int cc = c - NH;
        float rv = sigmoidf_(v + br[cc]);
        rhb[(size_t)m * NH + cc] = f2bf(rv * hf[(size_t)m * NH + cc]);
      }
    }
  }
}

__global__ void __launch_bounds__(256)
gru_phase2(const float* __restrict__ x, const ushort_t* __restrict__ B2t,
           ushort_t* __restrict__ hb, const ushort_t* __restrict__ rhb,
           float* __restrict__ hf, const float* __restrict__ zfb,
           const float* __restrict__ bb, float* __restrict__ out, int t) {
  __shared__ __align__(16) char smem[16384];
  const int tid  = threadIdx.x;
  const int bid  = blockIdx.x;
  const int lane = tid & 63;
  const int w    = tid >> 6;
  const int wm   = w >> 1, wn = w & 1;
  const int m0   = (bid >> 5) * 32;
  const int n2   = (bid & 31) * 32;
  const int l15  = lane & 15, l4 = lane >> 4;

  f32x4 acc = {0.f, 0.f, 0.f, 0.f};
  for (int kb = 0; kb < KK / BK; ++kb) {
    const int kbase = kb * BK;
#pragma unroll
    for (int i = 0; i < 2; ++i) {
      int c = tid + (i << 8);
      int r = c >> 4, kc = (c & 15) << 3;
      int m = m0 + r, k = kbase + kc;
      i32x4 v;
      if (k < NH) {
        v = *reinterpret_cast<const i32x4*>(rhb + (size_t)m * NH + k);
      } else {
        const float* xp = x + (size_t)m * (NT * ND) + (size_t)t * ND + (k - NH);
        f32x4 f0 = *reinterpret_cast<const f32x4*>(xp);
        f32x4 f1 = *reinterpret_cast<const f32x4*>(xp + 4);
        v[0] = pack2(f0[0], f0[1]); v[1] = pack2(f0[2], f0[3]);
        v[2] = pack2(f1[0], f1[1]); v[3] = pack2(f1[2], f1[3]);
      }
      int off = (r << 8) + (((kc << 1)) ^ ((r & 7) << 4));
      *reinterpret_cast<i32x4*>(&smem[off]) = v;
    }
#pragma unroll
    for (int i = 0; i < 2; ++i) {
      int c = tid + (i << 8);
      int n = c >> 4, kc = (c & 15) << 3;
      i32x4 v = *reinterpret_cast<const i32x4*>(B2t + (size_t)(n2 + n) * KK + kbase + kc);
      int off = 8192 + (n << 8) + (((kc << 1)) ^ ((n & 7) << 4));
      *reinterpret_cast<i32x4*>(&smem[off]) = v;
    }
    __syncthreads();
#pragma unroll
    for (int ks = 0; ks < 4; ++ks) {
      int kbyte = ks * 64 + l4 * 16;
      int ra = wm * 16 + l15;
      short8 a = *reinterpret_cast<short8*>(&smem[(ra << 8) + (kbyte ^ ((ra & 7) << 4))]);
      int nb = wn * 16 + l15;
      short8 b0 = *reinterpret_cast<short8*>(&smem[8192 + (nb << 8) + (kbyte ^ ((nb & 7) << 4))]);
      acc = __builtin_amdgcn_mfma_f32_16x16x32_bf16(a, b0, acc, 0, 0, 0);
    }
    __syncthreads();
  }
  int mrow = m0 + wm * 16 + l4 * 4;
  int c = n2 + wn * 16 + l15;
#pragma unroll
  for (int j = 0; j < 4; ++j) {
    int m = mrow + j;
    size_t idx = (size_t)m * NH + c;
    float hc = tanhf_(acc[j] + bb[c]);
    float zv = zfb[idx];
    float hn = (1.f - zv) * hf[idx] + zv * hc;
    hf[idx] = hn;
    hb[idx] = f2bf(hn);
    if (t == NT - 1) out[idx] = hn;
  }
}

// ===========================================================================
extern "C" void kernel_launch(void* const* d_in, const int* in_sizes, int n_in,
                              void* d_out, int out_size, void* d_ws, size_t ws_size,
                              hipStream_t stream) {
  const float* x  = (const float*)d_in[0];
  const float* W  = (const float*)d_in[1];
  const float* U  = (const float*)d_in[2];
  const float* Wz = (const float*)d_in[3];
  const float* Uz = (const float*)d_in[4];
  const float* Wr = (const float*)d_in[5];
  const float* Ur = (const float*)d_in[6];
  const float* bb = (const float*)d_in[7];
  const float* bz = (const float*)d_in[8];
  const float* br = (const float*)d_in[9];
  float* out = (float*)d_out;
  char* ws = (char*)d_ws;

  // fast-path workspace layout
  ushort_t* Bu1   = (ushort_t*)(ws);                  //  4,194,304
  ushort_t* Bu2   = (ushort_t*)(ws + 4194304);        //  2,097,152
  ushort_t* Bx    = (ushort_t*)(ws + 6291456);        //  3,145,728
  ushort_t* hb    = (ushort_t*)(ws + 9437184);        //    524,288
  ushort_t* rhb   = (ushort_t*)(ws + 9961472);        //    524,288
  float*    hf    = (float*)   (ws + 10485760);       //  1,048,576
  float*    zfb   = (float*)   (ws + 11534336);       //  1,048,576
  unsigned* flags = (unsigned*)(ws + 12582912);       //      4,096
  ushort_t* Gx    = (ushort_t*)(ws + 12587008);       // 805,306,368 -> 817,893,376

  const bool fast = (ws_size >= (size_t)817893376ULL);

  if (fast) {
    (void)hipFuncSetAttribute(reinterpret_cast<const void*>(&gru_v4),
                              hipFuncAttributeMaxDynamicSharedMemorySize, 98304);
    hipLaunchKernelGGL(repackT, dim3(16, 16), dim3(256), 0, stream, Uz, Bu1, NH);
    hipLaunchKernelGGL(repackT, dim3(16, 16), dim3(256), 0, stream, Ur, Bu1 + (size_t)NH * NH, NH);
    hipLaunchKernelGGL(repackT, dim3(16, 16), dim3(256), 0, stream, U,  Bu2, NH);
    hipLaunchKernelGGL(repackT, dim3(8, 16),  dim3(256), 0, stream, Wz, Bx, ND);
    hipLaunchKernelGGL(repackT, dim3(8, 16),  dim3(256), 0, stream, Wr, Bx + (size_t)NH * ND, ND);
    hipLaunchKernelGGL(repackT, dim3(8, 16),  dim3(256), 0, stream, W,  Bx + (size_t)2 * NH * ND, ND);
    hipLaunchKernelGGL(init_fast, dim3(1024), dim3(256), 0, stream, hb, hf, flags);
    hipLaunchKernelGGL(gxgemm, dim3(2048, 48), dim3(256), 0, stream, x, Bx, bz, br, bb, Gx);
    hipLaunchKernelGGL(gru_v4, dim3(NBLK), dim3(512), 98304, stream,
                       Gx, Bu1, Bu2, hb, rhb, hf, zfb, flags, out);
  } else {
    // fallback: proven round-2 per-step path
    ushort_t* B1t  = (ushort_t*)(ws);
    ushort_t* B2t  = (ushort_t*)(ws + 6291456);
    ushort_t* hb2  = (ushort_t*)(ws + 9437184);
    ushort_t* rhb2 = (ushort_t*)(ws + 9961472);
    float*    hf2  = (float*)   (ws + 10485760);
    float*    zfb2 = (float*)   (ws + 11534336);
    hipLaunchKernelGGL(repack_weights, dim3(24, 32, 2), dim3(256), 0, stream,
                       U, W, Uz, Wz, Ur, Wr, B1t, B2t);
    hipLaunchKernelGGL(init_state, dim3(1024), dim3(256), 0, stream, hb2, hf2);
    for (int t = 0; t < NT; ++t) {
      hipLaunchKernelGGL(gru_phase1, dim3(256), dim3(256), 0, stream,
                         x, B1t, hb2, rhb2, hf2, zfb2, bz, br, t);
      hipLaunchKernelGGL(gru_phase2, dim3(256), dim3(256), 0, stream,
                         x, B2t, hb2, rhb2, hf2, zfb2, bb, out, t);
    }
  }
}